// Round 9
// baseline (132.918 us; speedup 1.0000x reference)
//
#include <hip/hip_runtime.h>

// Problem constants
#define S_LEN   1024
#define NH      16
#define HD      64
#define BATCHN  8
#define DMODEL  1024
#define HALF_W  16          // window//2

typedef __attribute__((ext_vector_type(8))) short bf16x8;   // 8 bf16 = 4 VGPRs
typedef __attribute__((ext_vector_type(4))) float f32x4;

__device__ __forceinline__ unsigned short f2bf(float f) {
  unsigned u = __builtin_bit_cast(unsigned, f);
  u += 0x7fffu + ((u >> 16) & 1u);          // round-to-nearest-even
  return (unsigned short)(u >> 16);
}
__device__ __forceinline__ float bf2f(unsigned short h) {
  return __builtin_bit_cast(float, ((unsigned)h) << 16);
}

__device__ __forceinline__ void gload_lds16(const void* g, void* l) {
  __builtin_amdgcn_global_load_lds(
      (const __attribute__((address_space(1))) void*)g,
      (__attribute__((address_space(3))) void*)l, 16, 0, 0);
}

// ---------------------------------------------------------------------------
// f32 -> bf16 conversion (vectorized)
// ---------------------------------------------------------------------------
__global__ __launch_bounds__(256) void cvt_bf16_kernel(
    const float* __restrict__ in, unsigned short* __restrict__ out, int n4) {
  int t = blockIdx.x * 256 + threadIdx.x;
  if (t >= n4) return;
  float4 v = reinterpret_cast<const float4*>(in)[t];
  ushort4 o = make_ushort4(f2bf(v.x), f2bf(v.y), f2bf(v.z), f2bf(v.w));
  reinterpret_cast<ushort4*>(out)[t] = o;
}

// ---------------------------------------------------------------------------
// Deep-pipelined GEMM: C[M,N] = A[M,1024] * B[N,1024]^T + bias[N]
// CHN=2: tile 256x256, 8 waves 2Mx4N, per-wave 128x64 (in-proj).
// CHN=1: tile 128x256, 8 waves 2Mx4N, per-wave 64x64  (out-proj, grid 256).
// R8 swizzle (verified: conflicts 4.7e6 -> 0) retained.
// R9: m201-style issue order — stages first, ALL pair reads up-front
// (ph0's 8, sched_barrier, ph1's 4), split waits lgkmcnt(4)/(0) so ph1's
// LDS latency hides under ph0's MFMA cluster. Ledger unchanged.
// ---------------------------------------------------------------------------
#define MFMA_BF16 __builtin_amdgcn_mfma_f32_16x16x32_bf16

template <int OUT_BF16, int CHN>
__global__ __launch_bounds__(512, 2) void gemmdp_kernel(
    const unsigned short* __restrict__ A,
    const unsigned short* __restrict__ B,
    const float* __restrict__ bias,
    void* __restrict__ Cv,
    int N, int gy) {
  __shared__ __align__(16) unsigned short sA[2][2][CHN * 4096];
  __shared__ __align__(16) unsigned short sB[2][2][8192];

  const int tid  = threadIdx.x;
  const int lane = tid & 63;
  const int wid  = tid >> 6;       // 0..7
  const int wm   = wid >> 2;       // 0..1
  const int wn   = wid & 3;        // 0..3
  const int lgrp = lane >> 4;      // 0..3
  const int l15  = lane & 15;

  // T1: bijective XCD swizzle (grid % 8 == 0)
  const int nwg = gridDim.x;
  const int cpx = nwg >> 3;
  const int sid = (blockIdx.x & 7) * cpx + (blockIdx.x >> 3);
  const int tileM = (sid / gy) * (CHN * 128);
  const int tileN = (sid % gy) * 256;

  // stage source: thread t -> slab row t>>2 (0..127), chunk t&3.
  // SOURCE col chunk pre-swizzled by f(row) = (row>>1)&3 = (t>>3)&3.
  const int srow = tid >> 2;
  const int scol = ((tid & 3) ^ ((tid >> 3) & 3)) * 8;
  const unsigned short* gA_s = A + (size_t)(tileM + srow) * 1024 + scol;
  const unsigned short* gB_s = B + (size_t)(tileN + srow) * 1024 + scol;

  // fragment read bases: chunk = lgrp ^ ((l15>>1)&3)  (conflict-free 2-way)
  const int fch  = (lgrp ^ ((l15 >> 1) & 3)) * 8;
  const int arow = (wm * (CHN * 64) + l15) * 32 + fch;
  const int brow = (wn * 64 + l15) * 32 + fch;

  f32x4 acc[CHN * 4][4] = {};
  bf16x8 nb0 = {}, nb1 = {}, nb2 = {}, nb3 = {};

#define SSA(KT, BUF, KH) do {                                              \
    const unsigned short* _sa = gA_s + (KT) * 64 + (KH) * 32;              \
    gload_lds16(_sa, &sA[BUF][KH][wid * 512]);                             \
    if constexpr (CHN == 2)                                                \
      gload_lds16(_sa + 131072, &sA[BUF][KH][4096 + wid * 512]);           \
  } while (0)
#define SSB(KT, BUF, KH) do {                                              \
    const unsigned short* _sb = gB_s + (KT) * 64 + (KH) * 32;              \
    gload_lds16(_sb, &sB[BUF][KH][wid * 512]);                             \
    gload_lds16(_sb + 131072, &sB[BUF][KH][4096 + wid * 512]);             \
  } while (0)

#define GATE_S do {                                                        \
    if constexpr (CHN == 2) asm volatile("s_waitcnt vmcnt(8)" ::: "memory");\
    else                    asm volatile("s_waitcnt vmcnt(6)" ::: "memory");\
    __builtin_amdgcn_sched_barrier(0);                                     \
    __builtin_amdgcn_s_barrier(); } while (0)
#define GATE_H do {                                                        \
    if constexpr (CHN == 2) asm volatile("s_waitcnt vmcnt(4)" ::: "memory");\
    else                    asm volatile("s_waitcnt vmcnt(3)" ::: "memory");\
    __builtin_amdgcn_sched_barrier(0);                                     \
    __builtin_amdgcn_s_barrier(); } while (0)
#define GATE_Z do {                                                        \
    asm volatile("s_waitcnt vmcnt(0)" ::: "memory");                       \
    __builtin_amdgcn_sched_barrier(0);                                     \
    __builtin_amdgcn_s_barrier(); } while (0)

#define MFMA16(CH)                                                         \
    acc[(CH)*4+0][0] = MFMA_BF16(a0_, nb0, acc[(CH)*4+0][0], 0, 0, 0);     \
    acc[(CH)*4+0][1] = MFMA_BF16(a0_, nb1, acc[(CH)*4+0][1], 0, 0, 0);     \
    acc[(CH)*4+0][2] = MFMA_BF16(a0_, nb2, acc[(CH)*4+0][2], 0, 0, 0);     \
    acc[(CH)*4+0][3] = MFMA_BF16(a0_, nb3, acc[(CH)*4+0][3], 0, 0, 0);     \
    acc[(CH)*4+1][0] = MFMA_BF16(a1_, nb0, acc[(CH)*4+1][0], 0, 0, 0);     \
    acc[(CH)*4+1][1] = MFMA_BF16(a1_, nb1, acc[(CH)*4+1][1], 0, 0, 0);     \
    acc[(CH)*4+1][2] = MFMA_BF16(a1_, nb2, acc[(CH)*4+1][2], 0, 0, 0);     \
    acc[(CH)*4+1][3] = MFMA_BF16(a1_, nb3, acc[(CH)*4+1][3], 0, 0, 0);     \
    acc[(CH)*4+2][0] = MFMA_BF16(a2_, nb0, acc[(CH)*4+2][0], 0, 0, 0);     \
    acc[(CH)*4+2][1] = MFMA_BF16(a2_, nb1, acc[(CH)*4+2][1], 0, 0, 0);     \
    acc[(CH)*4+2][2] = MFMA_BF16(a2_, nb2, acc[(CH)*4+2][2], 0, 0, 0);     \
    acc[(CH)*4+2][3] = MFMA_BF16(a2_, nb3, acc[(CH)*4+2][3], 0, 0, 0);     \
    acc[(CH)*4+3][0] = MFMA_BF16(a3_, nb0, acc[(CH)*4+3][0], 0, 0, 0);     \
    acc[(CH)*4+3][1] = MFMA_BF16(a3_, nb1, acc[(CH)*4+3][1], 0, 0, 0);     \
    acc[(CH)*4+3][2] = MFMA_BF16(a3_, nb2, acc[(CH)*4+3][2], 0, 0, 0);     \
    acc[(CH)*4+3][3] = MFMA_BF16(a3_, nb3, acc[(CH)*4+3][3], 0, 0, 0);

  // CHN=2 pair: stages first, 12 reads up-front (order pinned), split waits.
#define DOPAIR2(BUF, KH, STGA, STGB) do {                                  \
    STGA; STGB;                                                            \
    const unsigned short* _pa0 = &sA[BUF][KH][arow];                       \
    const unsigned short* _pb  = &sB[BUF][KH][brow];                       \
    bf16x8 p00 = *(const bf16x8*)(_pa0);                                   \
    bf16x8 p01 = *(const bf16x8*)(_pa0 + 512);                             \
    bf16x8 p02 = *(const bf16x8*)(_pa0 + 1024);                            \
    bf16x8 p03 = *(const bf16x8*)(_pa0 + 1536);                            \
    nb0 = *(const bf16x8*)(_pb);        nb1 = *(const bf16x8*)(_pb + 512); \
    nb2 = *(const bf16x8*)(_pb + 1024); nb3 = *(const bf16x8*)(_pb + 1536);\
    __builtin_amdgcn_sched_barrier(0);                                     \
    const unsigned short* _pa1 = &sA[BUF][KH][arow + 2048];                \
    bf16x8 p10 = *(const bf16x8*)(_pa1);                                   \
    bf16x8 p11 = *(const bf16x8*)(_pa1 + 512);                             \
    bf16x8 p12 = *(const bf16x8*)(_pa1 + 1024);                            \
    bf16x8 p13 = *(const bf16x8*)(_pa1 + 1536);                            \
    asm volatile("s_waitcnt lgkmcnt(4)" ::: "memory");                     \
    __builtin_amdgcn_sched_barrier(0);                                     \
    __builtin_amdgcn_s_setprio(1);                                         \
    { bf16x8 a0_ = p00, a1_ = p01, a2_ = p02, a3_ = p03; MFMA16(0) }       \
    __builtin_amdgcn_s_setprio(0);                                         \
    asm volatile("s_waitcnt lgkmcnt(0)" ::: "memory");                     \
    __builtin_amdgcn_sched_barrier(0);                                     \
    __builtin_amdgcn_s_setprio(1);                                         \
    { bf16x8 a0_ = p10, a1_ = p11, a2_ = p12, a3_ = p13; MFMA16(1) }       \
    __builtin_amdgcn_s_setprio(0);                                         \
  } while (0)

  // CHN=1 pair: stages first, 8 reads, single wait.
#define DOPAIR1(BUF, KH, STGA, STGB) do {                                  \
    STGA; STGB;                                                            \
    const unsigned short* _pa0 = &sA[BUF][KH][arow];                       \
    const unsigned short* _pb  = &sB[BUF][KH][brow];                       \
    bf16x8 p00 = *(const bf16x8*)(_pa0);                                   \
    bf16x8 p01 = *(const bf16x8*)(_pa0 + 512);                             \
    bf16x8 p02 = *(const bf16x8*)(_pa0 + 1024);                            \
    bf16x8 p03 = *(const bf16x8*)(_pa0 + 1536);                            \
    nb0 = *(const bf16x8*)(_pb);        nb1 = *(const bf16x8*)(_pb + 512); \
    nb2 = *(const bf16x8*)(_pb + 1024); nb3 = *(const bf16x8*)(_pb + 1536);\
    asm volatile("s_waitcnt lgkmcnt(0)" ::: "memory");                     \
    __builtin_amdgcn_sched_barrier(0);                                     \
    __builtin_amdgcn_s_setprio(1);                                         \
    { bf16x8 a0_ = p00, a1_ = p01, a2_ = p02, a3_ = p03; MFMA16(0) }       \
    __builtin_amdgcn_s_setprio(0);                                         \
  } while (0)

#define DOPAIR(BUF, KH, STGA, STGB) do {                                   \
    if constexpr (CHN == 2) DOPAIR2(BUF, KH, STGA, STGB);                  \
    else                    DOPAIR1(BUF, KH, STGA, STGB); } while (0)
#define NOSTG ((void)0)

  // prologue: stage slabs 0,1,2 (slab = (kt,kh) A+B)
  SSA(0, 0, 0); SSB(0, 0, 0);
  SSA(0, 0, 1); SSB(0, 0, 1);
  SSA(1, 1, 0); SSB(1, 1, 0);

  // steady: pairs s = 0..27 (tiles 0..13); pair s stages slab s+3
#pragma unroll 1
  for (int kt = 0; kt < 14; kt += 2) {
    GATE_S; DOPAIR(0, 0, SSA(kt + 1, 1, 1), SSB(kt + 1, 1, 1));
    GATE_S; DOPAIR(0, 1, SSA(kt + 2, 0, 0), SSB(kt + 2, 0, 0));
    GATE_S; DOPAIR(1, 0, SSA(kt + 2, 0, 1), SSB(kt + 2, 0, 1));
    GATE_S; DOPAIR(1, 1, SSA(kt + 3, 1, 0), SSB(kt + 3, 1, 0));
  }
  // tail: tiles 14 (buf0) and 15 (buf1)
  GATE_S; DOPAIR(0, 0, SSA(15, 1, 1), SSB(15, 1, 1));
  GATE_S; DOPAIR(0, 1, NOSTG, NOSTG);
  GATE_H; DOPAIR(1, 0, NOSTG, NOSTG);
  GATE_Z; DOPAIR(1, 1, NOSTG, NOSTG);

#undef SSA
#undef SSB
#undef GATE_S
#undef GATE_H
#undef GATE_Z
#undef MFMA16
#undef DOPAIR2
#undef DOPAIR1
#undef DOPAIR
#undef NOSTG

  // epilogue: C/D layout col = lane&15 (B-row), row = lgrp*4 + rr (A-row)
#pragma unroll
  for (int nt = 0; nt < 4; ++nt) {
    const int col = tileN + wn * 64 + nt * 16 + l15;
    const float bs = bias[col];
#pragma unroll
    for (int ch = 0; ch < CHN; ++ch)
#pragma unroll
      for (int mt = 0; mt < 4; ++mt) {
        const int row0 = tileM + wm * (CHN * 64) + ch * 64 + mt * 16 + lgrp * 4;
#pragma unroll
        for (int rr = 0; rr < 4; ++rr) {
          float v = acc[ch * 4 + mt][nt][rr] + bs;
          if (OUT_BF16) {
            ((unsigned short*)Cv)[(size_t)(row0 + rr) * N + col] = f2bf(v);
          } else {
            ((float*)Cv)[(size_t)(row0 + rr) * N + col] = v;
          }
        }
      }
  }
}

// ---------------------------------------------------------------------------
// Windowed attention v3 (MFMA). Block = (b, h, 64-query tile), 4 waves.
// ---------------------------------------------------------------------------
#define KST 72    // sK/sQ stride (bf16): 144B rows -> 2-way bank alias (free)
#define PST 104   // sVT/sP stride (bf16): 208B rows -> uniform 2-way

__global__ __launch_bounds__(256) void attn_local_kernel(
    const unsigned short* __restrict__ qkv, unsigned short* __restrict__ ctx) {
  __shared__ __align__(16) unsigned short sKP[96 * KST];   // K, later P
  __shared__ __align__(16) unsigned short sQ[64 * KST];
  __shared__ __align__(16) unsigned short sVT[64 * PST];

  const int tid  = threadIdx.x;
  const int lane = tid & 63;
  const int wid  = tid >> 6;
  const int qc   = lane & 15;        // query col within wave's 16
  const int lgrp = lane >> 4;        // 0..3

  const int qb = blockIdx.x & 15;    // S/64 = 16
  const int h  = (blockIdx.x >> 4) & 15;
  const int b  = blockIdx.x >> 8;
  const int i0 = qb * 64;

  const unsigned short* hb = qkv + (size_t)b * S_LEN * 3072 + (size_t)h * HD;

  // ---- stage K [96][KST] and V^T [64][PST] ----
#pragma unroll
  for (int it = 0; it < 3; ++it) {
    int c  = it * 256 + tid;         // 0..767
    int r  = c >> 3;                 // key row 0..95
    int d0 = (c & 7) * 8;            // dim chunk
    int j  = i0 - 16 + r;
    bf16x8 kv = {}, vv = {};
    if (0 <= j && j < S_LEN) {
      const unsigned short* rp = hb + (size_t)j * 3072;
      kv = *reinterpret_cast<const bf16x8*>(rp + DMODEL + d0);
      vv = *reinterpret_cast<const bf16x8*>(rp + 2 * DMODEL + d0);
    }
    *reinterpret_cast<bf16x8*>(&sKP[r * KST + d0]) = kv;
#pragma unroll
    for (int jj = 0; jj < 8; ++jj) {
      int dd = (jj + c) & 7;
      sVT[(d0 + dd) * PST + r] = (unsigned short)vv[dd];
    }
  }
  // ---- stage Q [64][KST] ----
#pragma unroll
  for (int it = 0; it < 2; ++it) {
    int c  = it * 256 + tid;         // 0..511
    int r  = c >> 3;                 // query row 0..63
    int d0 = (c & 7) * 8;
    bf16x8 qv = *reinterpret_cast<const bf16x8*>(hb + (size_t)(i0 + r) * 3072 + d0);
    *reinterpret_cast<bf16x8*>(&sQ[r * KST + d0]) = qv;
  }
  __syncthreads();

  const int q0 = wid * 16;

  // ---- phase 1: S^T = K @ Q^T  (12 MFMA) ----
  bf16x8 bq[2];
#pragma unroll
  for (int ks = 0; ks < 2; ++ks)
    bq[ks] = *reinterpret_cast<const bf16x8*>(
        &sQ[(q0 + qc) * KST + ks * 32 + lgrp * 8]);

  f32x4 st[6] = {};
#pragma unroll
  for (int kt = 0; kt < 6; ++kt) {
#pragma unroll
    for (int ks = 0; ks < 2; ++ks) {
      bf16x8 fa = *reinterpret_cast<const bf16x8*>(
          &sKP[(kt * 16 + qc) * KST + ks * 32 + lgrp * 8]);
      st[kt] = __builtin_amdgcn_mfma_f32_16x16x32_bf16(fa, bq[ks], st[kt], 0, 0, 0);
    }
  }
  __syncthreads();   // all waves done reading sKP before P overlays it

  // ---- mask + softmax ----
  const int q = q0 + qc;
  float pv[6][4];
  float mx = -3.0e38f;
#pragma unroll
  for (int kt = 0; kt < 6; ++kt)
#pragma unroll
    for (int rr = 0; rr < 4; ++rr) {
      int kk = kt * 16 + lgrp * 4 + rr;     // local key 0..95
      int j  = i0 - 16 + kk;
      bool ok = (j >= 0) && (j < S_LEN) && (kk >= q) && (kk <= q + 32);
      float s = ok ? st[kt][rr] * 0.125f : -3.0e38f;
      pv[kt][rr] = s;
      mx = fmaxf(mx, s);
    }
  mx = fmaxf(mx, __shfl_xor(mx, 16, 64));
  mx = fmaxf(mx, __shfl_xor(mx, 32, 64));

  float rsum = 0.f;
#pragma unroll
  for (int kt = 0; kt < 6; ++kt)
#pragma unroll
    for (int rr = 0; rr < 4; ++rr) {
      float p = __expf(pv[kt][rr] - mx);
      pv[kt][rr] = p;
      rsum += p;
    }
  rsum += __shfl_xor(rsum, 16, 64);
  rsum += __shfl_xor(rsum, 32, 64);
  const float inv = 1.0f / rsum;

  // ---- write unnormalized P bf16 into sP = sKP, layout [q][k] stride PST ----
  unsigned short* sP = sKP;
#pragma unroll
  for (int kt = 0; kt < 6; ++kt) {
    ushort4 w = make_ushort4(f2bf(pv[kt][0]), f2bf(pv[kt][1]),
                             f2bf(pv[kt][2]), f2bf(pv[kt][3]));
    *reinterpret_cast<ushort4*>(&sP[(q0 + qc) * PST + kt * 16 + lgrp * 4]) = w;
  }

  // ---- phase 2: ctx^T = V^T @ P^T  (12 MFMA) ----
  bf16x8 pb[3];
#pragma unroll
  for (int ks = 0; ks < 3; ++ks)
    pb[ks] = *reinterpret_cast<const bf16x8*>(
        &sP[(q0 + qc) * PST + ks * 32 + lgrp * 8]);

  f32x4 ct[4] = {};
#pragma unroll
  for (int dt = 0; dt < 4; ++dt)
#pragma unroll
    for (int ks = 0; ks < 3; ++ks) {
      bf16x8 fa = *reinterpret_cast<const bf16x8*>(
          &sVT[(dt * 16 + qc) * PST + ks * 32 + lgrp * 8]);
      ct[dt] = __builtin_amdgcn_mfma_f32_16x16x32_bf16(fa, pb[ks], ct[dt], 0, 0, 0);
    }

  // ---- epilogue ----
  unsigned short* op =
      ctx + ((size_t)b * S_LEN + i0 + q0 + qc) * DMODEL + h * HD;
#pragma unroll
  for (int dt = 0; dt < 4; ++dt) {
    ushort4 w = make_ushort4(
        f2bf(ct[dt][0] * inv), f2bf(ct[dt][1] * inv),
        f2bf(ct[dt][2] * inv), f2bf(ct[dt][3] * inv));
    *reinterpret_cast<ushort4*>(op + dt * 16 + lgrp * 4) = w;
  }
}

// ---------------------------------------------------------------------------
extern "C" void kernel_launch(void* const* d_in, const int* in_sizes, int n_in,
                              void* d_out, int out_size, void* d_ws, size_t ws_size,
                              hipStream_t stream) {
  const float* x     = (const float*)d_in[0];
  const float* w_in  = (const float*)d_in[1];
  const float* b_in  = (const float*)d_in[2];
  const float* w_out = (const float*)d_in[3];
  const float* b_out = (const float*)d_in[4];
  float* out = (float*)d_out;

  // workspace layout (bf16 = ushort), total ~92 MB
  unsigned short* xb   = (unsigned short*)d_ws;
  unsigned short* wib  = xb  + (size_t)8192 * 1024;
  unsigned short* wob  = wib + (size_t)3072 * 1024;
  unsigned short* qkv  = wob + (size_t)1024 * 1024;
  unsigned short* ctxb = qkv + (size_t)8192 * 3072;

  cvt_bf16_kernel<<<8192, 256, 0, stream>>>(x, xb, (8192 * 1024) / 4);
  cvt_bf16_kernel<<<3072, 256, 0, stream>>>(w_in, wib, (3072 * 1024) / 4);
  cvt_bf16_kernel<<<1024, 256, 0, stream>>>(w_out, wob, (1024 * 1024) / 4);

  // QKV = x @ w_in^T + b_in -> [8192, 3072] bf16; 256x256 tiles, grid 32x12
  gemmdp_kernel<1, 2><<<384, 512, 0, stream>>>(
      xb, wib, b_in, (void*)qkv, 3072, 12);

  // windowed attention -> ctx [8192, 1024] bf16
  attn_local_kernel<<<BATCHN * NH * (S_LEN / 64), 256, 0, stream>>>(qkv, ctxb);

  // out = ctx @ w_out^T + b_out -> [8192, 1024] f32; 128x256 tiles, grid 64x4=256
  gemmdp_kernel<0, 1><<<256, 512, 0, stream>>>(
      ctxb, wob, b_out, (void*)out, 1024, 4);
}

// Round 10
// 121.199 us; speedup vs baseline: 1.0967x; 1.0967x over previous
//
#include <hip/hip_runtime.h>

// Problem constants
#define S_LEN   1024
#define NH      16
#define HD      64
#define BATCHN  8
#define DMODEL  1024
#define HALF_W  16          // window//2

typedef __attribute__((ext_vector_type(8))) short bf16x8;   // 8 bf16 = 4 VGPRs
typedef __attribute__((ext_vector_type(4))) float f32x4;

__device__ __forceinline__ unsigned short f2bf(float f) {
  unsigned u = __builtin_bit_cast(unsigned, f);
  u += 0x7fffu + ((u >> 16) & 1u);          // round-to-nearest-even
  return (unsigned short)(u >> 16);
}
__device__ __forceinline__ float bf2f(unsigned short h) {
  return __builtin_bit_cast(float, ((unsigned)h) << 16);
}

__device__ __forceinline__ void gload_lds16(const void* g, void* l) {
  __builtin_amdgcn_global_load_lds(
      (const __attribute__((address_space(1))) void*)g,
      (__attribute__((address_space(3))) void*)l, 16, 0, 0);
}

// ---------------------------------------------------------------------------
// f32 -> bf16 conversion (vectorized)
// ---------------------------------------------------------------------------
__global__ __launch_bounds__(256) void cvt_bf16_kernel(
    const float* __restrict__ in, unsigned short* __restrict__ out, int n4) {
  int t = blockIdx.x * 256 + threadIdx.x;
  if (t >= n4) return;
  float4 v = reinterpret_cast<const float4*>(in)[t];
  ushort4 o = make_ushort4(f2bf(v.x), f2bf(v.y), f2bf(v.z), f2bf(v.w));
  reinterpret_cast<ushort4*>(out)[t] = o;
}

#define MFMA_BF16 __builtin_amdgcn_mfma_f32_16x16x32_bf16

// ---------------------------------------------------------------------------
// In-proj GEMM (R10): C[8192,3072] = A[8192,1024] * B[3072,1024]^T + bias.
// Tile 256M x 384N -> grid 32x8 = 256 blocks = EXACTLY one CU round (was
// 384 = 1.5 rounds, ~25% tail waste). 8 waves (2M x 4N), per-wave 128x96:
// 48 MFMA per gate (vs 32), A-frags in two halves of 4 for VGPR headroom.
// K in 32-col slabs; 4 LDS slab-slots (160KB exactly); uniform 5 gloads/
// thread/slab; distance-3 prefetch; steady gate vmcnt(10); R8 swizzle.
// ---------------------------------------------------------------------------
__global__ __launch_bounds__(512, 2) void gemm_inproj_kernel(
    const unsigned short* __restrict__ A,
    const unsigned short* __restrict__ B,
    const float* __restrict__ bias,
    unsigned short* __restrict__ C) {
  // flat LDS: A slots 0..3 at s*8192 (256x32), B slots at 32768 + s*12288 (384x32)
  __shared__ __align__(16) unsigned short lds[81920];   // 160 KiB

  const int tid  = threadIdx.x;
  const int lane = tid & 63;
  const int wid  = tid >> 6;       // 0..7
  const int wm   = wid >> 2;       // 0..1  (M: 2 x 128)
  const int wn   = wid & 3;        // 0..3  (N: 4 x 96)
  const int lgrp = lane >> 4;      // 0..3
  const int l15  = lane & 15;

  // T1: bijective XCD swizzle (nwg = 256)
  const int sid = (blockIdx.x & 7) * 32 + (blockIdx.x >> 3);
  const int tileM = (sid >> 3) * 256;    // 32 M-tiles
  const int tileN = (sid & 7) * 384;     // 8 N-tiles

  // stage source: thread t -> row t>>2 (0..127), chunk t&3,
  // source col pre-swizzled by f(row) = (row>>1)&3 = (t>>3)&3
  const int srow = tid >> 2;
  const int scol = ((tid & 3) ^ ((tid >> 3) & 3)) * 8;
  const unsigned short* gA_s = A + (size_t)(tileM + srow) * 1024 + scol;
  const unsigned short* gB_s = B + (size_t)(tileN + srow) * 1024 + scol;

  // fragment read bases: chunk = lgrp ^ ((l15>>1)&3)  (conflict-free 2-way)
  const int fch  = (lgrp ^ ((l15 >> 1) & 3)) * 8;
  const int arow = (wm * 128 + l15) * 32 + fch;
  const int brow = (wn * 96 + l15) * 32 + fch;

  f32x4 acc[48] = {};   // [mt 0..7][nt 0..5] -> acc[mt*6+nt]

  // slab s covers k in [32s, 32s+32); slot = s&3; 5 gloads/thread
#define STG(S) do { const int _q = (S) & 3;                                \
    const unsigned short* _ga = gA_s + (S) * 32;                           \
    const unsigned short* _gb = gB_s + (S) * 32;                           \
    gload_lds16(_ga,          &lds[_q * 8192 + tid * 8]);                  \
    gload_lds16(_ga + 131072, &lds[_q * 8192 + 4096 + tid * 8]);           \
    gload_lds16(_gb,          &lds[32768 + _q * 12288 + tid * 8]);         \
    gload_lds16(_gb + 131072, &lds[32768 + _q * 12288 + 4096 + tid * 8]);  \
    gload_lds16(_gb + 262144, &lds[32768 + _q * 12288 + 8192 + tid * 8]);  \
  } while (0)

#define M24(MB)                                                            \
    acc[(MB+0)*6+0] = MFMA_BF16(a0_, b0_, acc[(MB+0)*6+0], 0, 0, 0);       \
    acc[(MB+0)*6+1] = MFMA_BF16(a0_, b1_, acc[(MB+0)*6+1], 0, 0, 0);       \
    acc[(MB+0)*6+2] = MFMA_BF16(a0_, b2_, acc[(MB+0)*6+2], 0, 0, 0);       \
    acc[(MB+0)*6+3] = MFMA_BF16(a0_, b3_, acc[(MB+0)*6+3], 0, 0, 0);       \
    acc[(MB+0)*6+4] = MFMA_BF16(a0_, b4_, acc[(MB+0)*6+4], 0, 0, 0);       \
    acc[(MB+0)*6+5] = MFMA_BF16(a0_, b5_, acc[(MB+0)*6+5], 0, 0, 0);       \
    acc[(MB+1)*6+0] = MFMA_BF16(a1_, b0_, acc[(MB+1)*6+0], 0, 0, 0);       \
    acc[(MB+1)*6+1] = MFMA_BF16(a1_, b1_, acc[(MB+1)*6+1], 0, 0, 0);       \
    acc[(MB+1)*6+2] = MFMA_BF16(a1_, b2_, acc[(MB+1)*6+2], 0, 0, 0);       \
    acc[(MB+1)*6+3] = MFMA_BF16(a1_, b3_, acc[(MB+1)*6+3], 0, 0, 0);       \
    acc[(MB+1)*6+4] = MFMA_BF16(a1_, b4_, acc[(MB+1)*6+4], 0, 0, 0);       \
    acc[(MB+1)*6+5] = MFMA_BF16(a1_, b5_, acc[(MB+1)*6+5], 0, 0, 0);       \
    acc[(MB+2)*6+0] = MFMA_BF16(a2_, b0_, acc[(MB+2)*6+0], 0, 0, 0);       \
    acc[(MB+2)*6+1] = MFMA_BF16(a2_, b1_, acc[(MB+2)*6+1], 0, 0, 0);       \
    acc[(MB+2)*6+2] = MFMA_BF16(a2_, b2_, acc[(MB+2)*6+2], 0, 0, 0);       \
    acc[(MB+2)*6+3] = MFMA_BF16(a2_, b3_, acc[(MB+2)*6+3], 0, 0, 0);       \
    acc[(MB+2)*6+4] = MFMA_BF16(a2_, b4_, acc[(MB+2)*6+4], 0, 0, 0);       \
    acc[(MB+2)*6+5] = MFMA_BF16(a2_, b5_, acc[(MB+2)*6+5], 0, 0, 0);       \
    acc[(MB+3)*6+0] = MFMA_BF16(a3_, b0_, acc[(MB+3)*6+0], 0, 0, 0);       \
    acc[(MB+3)*6+1] = MFMA_BF16(a3_, b1_, acc[(MB+3)*6+1], 0, 0, 0);       \
    acc[(MB+3)*6+2] = MFMA_BF16(a3_, b2_, acc[(MB+3)*6+2], 0, 0, 0);       \
    acc[(MB+3)*6+3] = MFMA_BF16(a3_, b3_, acc[(MB+3)*6+3], 0, 0, 0);       \
    acc[(MB+3)*6+4] = MFMA_BF16(a3_, b4_, acc[(MB+3)*6+4], 0, 0, 0);       \
    acc[(MB+3)*6+5] = MFMA_BF16(a3_, b5_, acc[(MB+3)*6+5], 0, 0, 0);

  // prologue: slabs 0,1,2 -> 15 outstanding
  STG(0); STG(1); STG(2);

#pragma unroll 1
  for (int p = 0; p < 32; ++p) {
    // gate: keep 2 slabs (10 loads) in flight; drain at tail
    if (p < 30)       { asm volatile("s_waitcnt vmcnt(10)" ::: "memory"); }
    else if (p == 30) { asm volatile("s_waitcnt vmcnt(5)"  ::: "memory"); }
    else              { asm volatile("s_waitcnt vmcnt(0)"  ::: "memory"); }
    __builtin_amdgcn_sched_barrier(0);
    __builtin_amdgcn_s_barrier();

    if (p <= 28) STG(p + 3);

    const int slot = p & 3;
    const unsigned short* pa = &lds[slot * 8192 + arow];
    const unsigned short* pb = &lds[32768 + slot * 12288 + brow];

    bf16x8 b0_ = *(const bf16x8*)(pb);
    bf16x8 b1_ = *(const bf16x8*)(pb + 512);
    bf16x8 b2_ = *(const bf16x8*)(pb + 1024);
    bf16x8 b3_ = *(const bf16x8*)(pb + 1536);
    bf16x8 b4_ = *(const bf16x8*)(pb + 2048);
    bf16x8 b5_ = *(const bf16x8*)(pb + 2560);
    bf16x8 a0_ = *(const bf16x8*)(pa);
    bf16x8 a1_ = *(const bf16x8*)(pa + 512);
    bf16x8 a2_ = *(const bf16x8*)(pa + 1024);
    bf16x8 a3_ = *(const bf16x8*)(pa + 1536);
    asm volatile("s_waitcnt lgkmcnt(0)" ::: "memory");
    __builtin_amdgcn_sched_barrier(0);
    __builtin_amdgcn_s_setprio(1);
    M24(0)
    __builtin_amdgcn_s_setprio(0);

    a0_ = *(const bf16x8*)(pa + 2048);
    a1_ = *(const bf16x8*)(pa + 2560);
    a2_ = *(const bf16x8*)(pa + 3072);
    a3_ = *(const bf16x8*)(pa + 3584);
    asm volatile("s_waitcnt lgkmcnt(0)" ::: "memory");
    __builtin_amdgcn_sched_barrier(0);
    __builtin_amdgcn_s_setprio(1);
    M24(4)
    __builtin_amdgcn_s_setprio(0);
  }
#undef STG
#undef M24

  // epilogue: C/D layout col = lane&15 (B-row), row = lgrp*4 + rr (A-row)
#pragma unroll
  for (int nt = 0; nt < 6; ++nt) {
    const int col = tileN + wn * 96 + nt * 16 + l15;
    const float bs = bias[col];
#pragma unroll
    for (int mt = 0; mt < 8; ++mt) {
      const int row0 = tileM + wm * 128 + mt * 16 + lgrp * 4;
#pragma unroll
      for (int rr = 0; rr < 4; ++rr)
        C[(size_t)(row0 + rr) * 3072 + col] = f2bf(acc[mt * 6 + nt][rr] + bs);
    }
  }
}

// ---------------------------------------------------------------------------
// Out-proj GEMM (unchanged R8 structure, CHN=1): tile 128x256, grid 256.
// ---------------------------------------------------------------------------
__global__ __launch_bounds__(512, 2) void gemm_outproj_kernel(
    const unsigned short* __restrict__ A,
    const unsigned short* __restrict__ B,
    const float* __restrict__ bias,
    float* __restrict__ Cv) {
  __shared__ __align__(16) unsigned short sA[2][2][4096];
  __shared__ __align__(16) unsigned short sB[2][2][8192];

  const int tid  = threadIdx.x;
  const int lane = tid & 63;
  const int wid  = tid >> 6;
  const int wm   = wid >> 2;       // 0..1
  const int wn   = wid & 3;        // 0..3
  const int lgrp = lane >> 4;
  const int l15  = lane & 15;

  const int sid = (blockIdx.x & 7) * 32 + (blockIdx.x >> 3);   // nwg = 256
  const int tileM = (sid >> 2) * 128;   // 64 M-tiles
  const int tileN = (sid & 3) * 256;    // 4 N-tiles

  const int srow = tid >> 2;
  const int scol = ((tid & 3) ^ ((tid >> 3) & 3)) * 8;
  const unsigned short* gA_s = A + (size_t)(tileM + srow) * 1024 + scol;
  const unsigned short* gB_s = B + (size_t)(tileN + srow) * 1024 + scol;

  const int fch  = (lgrp ^ ((l15 >> 1) & 3)) * 8;
  const int arow = (wm * 64 + l15) * 32 + fch;
  const int brow = (wn * 64 + l15) * 32 + fch;

  f32x4 acc[4][4] = {};

#define SSA(KT, BUF, KH) do {                                              \
    gload_lds16(gA_s + (KT) * 64 + (KH) * 32, &sA[BUF][KH][wid * 512]);    \
  } while (0)
#define SSB(KT, BUF, KH) do {                                              \
    const unsigned short* _sb = gB_s + (KT) * 64 + (KH) * 32;              \
    gload_lds16(_sb,          &sB[BUF][KH][wid * 512]);                    \
    gload_lds16(_sb + 131072, &sB[BUF][KH][4096 + wid * 512]);             \
  } while (0)

#define GATE(NSTR) do {                                                    \
    asm volatile("s_waitcnt vmcnt(" NSTR ")" ::: "memory");                \
    __builtin_amdgcn_sched_barrier(0);                                     \
    __builtin_amdgcn_s_barrier(); } while (0)

#define PH1(BUF, KH, STGA, STGB) do {                                      \
    STGA; STGB;                                                            \
    const unsigned short* _pa = &sA[BUF][KH][arow];                        \
    const unsigned short* _pb = &sB[BUF][KH][brow];                        \
    bf16x8 a0_ = *(const bf16x8*)(_pa);                                    \
    bf16x8 a1_ = *(const bf16x8*)(_pa + 512);                              \
    bf16x8 a2_ = *(const bf16x8*)(_pa + 1024);                             \
    bf16x8 a3_ = *(const bf16x8*)(_pa + 1536);                             \
    bf16x8 nb0 = *(const bf16x8*)(_pb);                                    \
    bf16x8 nb1 = *(const bf16x8*)(_pb + 512);                              \
    bf16x8 nb2 = *(const bf16x8*)(_pb + 1024);                             \
    bf16x8 nb3 = *(const bf16x8*)(_pb + 1536);                             \
    asm volatile("s_waitcnt lgkmcnt(0)" ::: "memory");                     \
    __builtin_amdgcn_sched_barrier(0);                                     \
    __builtin_amdgcn_s_setprio(1);                                         \
    acc[0][0] = MFMA_BF16(a0_, nb0, acc[0][0], 0, 0, 0);                   \
    acc[0][1] = MFMA_BF16(a0_, nb1, acc[0][1], 0, 0, 0);                   \
    acc[0][2] = MFMA_BF16(a0_, nb2, acc[0][2], 0, 0, 0);                   \
    acc[0][3] = MFMA_BF16(a0_, nb3, acc[0][3], 0, 0, 0);                   \
    acc[1][0] = MFMA_BF16(a1_, nb0, acc[1][0], 0, 0, 0);                   \
    acc[1][1] = MFMA_BF16(a1_, nb1, acc[1][1], 0, 0, 0);                   \
    acc[1][2] = MFMA_BF16(a1_, nb2, acc[1][2], 0, 0, 0);                   \
    acc[1][3] = MFMA_BF16(a1_, nb3, acc[1][3], 0, 0, 0);                   \
    acc[2][0] = MFMA_BF16(a2_, nb0, acc[2][0], 0, 0, 0);                   \
    acc[2][1] = MFMA_BF16(a2_, nb1, acc[2][1], 0, 0, 0);                   \
    acc[2][2] = MFMA_BF16(a2_, nb2, acc[2][2], 0, 0, 0);                   \
    acc[2][3] = MFMA_BF16(a2_, nb3, acc[2][3], 0, 0, 0);                   \
    acc[3][0] = MFMA_BF16(a3_, nb0, acc[3][0], 0, 0, 0);                   \
    acc[3][1] = MFMA_BF16(a3_, nb1, acc[3][1], 0, 0, 0);                   \
    acc[3][2] = MFMA_BF16(a3_, nb2, acc[3][2], 0, 0, 0);                   \
    acc[3][3] = MFMA_BF16(a3_, nb3, acc[3][3], 0, 0, 0);                   \
    __builtin_amdgcn_s_setprio(0);                                         \
  } while (0)
#define NOSTG ((void)0)

  SSA(0, 0, 0); SSB(0, 0, 0);
  SSA(0, 0, 1); SSB(0, 0, 1);
  SSA(1, 1, 0); SSB(1, 1, 0);

#pragma unroll 1
  for (int kt = 0; kt < 14; kt += 2) {
    GATE("6"); PH1(0, 0, SSA(kt + 1, 1, 1), SSB(kt + 1, 1, 1));
    GATE("6"); PH1(0, 1, SSA(kt + 2, 0, 0), SSB(kt + 2, 0, 0));
    GATE("6"); PH1(1, 0, SSA(kt + 2, 0, 1), SSB(kt + 2, 0, 1));
    GATE("6"); PH1(1, 1, SSA(kt + 3, 1, 0), SSB(kt + 3, 1, 0));
  }
  GATE("6"); PH1(0, 0, SSA(15, 1, 1), SSB(15, 1, 1));
  GATE("6"); PH1(0, 1, NOSTG, NOSTG);
  GATE("3"); PH1(1, 0, NOSTG, NOSTG);
  GATE("0"); PH1(1, 1, NOSTG, NOSTG);

#undef SSA
#undef SSB
#undef GATE
#undef PH1
#undef NOSTG

#pragma unroll
  for (int nt = 0; nt < 4; ++nt) {
    const int col = tileN + wn * 64 + nt * 16 + l15;
    const float bs = bias[col];
#pragma unroll
    for (int mt = 0; mt < 4; ++mt) {
      const int row0 = tileM + wm * 64 + mt * 16 + lgrp * 4;
#pragma unroll
      for (int rr = 0; rr < 4; ++rr)
        Cv[(size_t)(row0 + rr) * 1024 + col] = acc[mt][nt][rr] + bs;
    }
  }
}

// ---------------------------------------------------------------------------
// Windowed attention v3 (MFMA). Block = (b, h, 64-query tile), 4 waves.
// ---------------------------------------------------------------------------
#define KST 72    // sK/sQ stride (bf16): 144B rows -> 2-way bank alias (free)
#define PST 104   // sVT/sP stride (bf16): 208B rows -> uniform 2-way

__global__ __launch_bounds__(256) void attn_local_kernel(
    const unsigned short* __restrict__ qkv, unsigned short* __restrict__ ctx) {
  __shared__ __align__(16) unsigned short sKP[96 * KST];   // K, later P
  __shared__ __align__(16) unsigned short sQ[64 * KST];
  __shared__ __align__(16) unsigned short sVT[64 * PST];

  const int tid  = threadIdx.x;
  const int lane = tid & 63;
  const int wid  = tid >> 6;
  const int qc   = lane & 15;        // query col within wave's 16
  const int lgrp = lane >> 4;        // 0..3

  const int qb = blockIdx.x & 15;    // S/64 = 16
  const int h  = (blockIdx.x >> 4) & 15;
  const int b  = blockIdx.x >> 8;
  const int i0 = qb * 64;

  const unsigned short* hb = qkv + (size_t)b * S_LEN * 3072 + (size_t)h * HD;

  // ---- stage K [96][KST] and V^T [64][PST] ----
#pragma unroll
  for (int it = 0; it < 3; ++it) {
    int c  = it * 256 + tid;         // 0..767
    int r  = c >> 3;                 // key row 0..95
    int d0 = (c & 7) * 8;            // dim chunk
    int j  = i0 - 16 + r;
    bf16x8 kv = {}, vv = {};
    if (0 <= j && j < S_LEN) {
      const unsigned short* rp = hb + (size_t)j * 3072;
      kv = *reinterpret_cast<const bf16x8*>(rp + DMODEL + d0);
      vv = *reinterpret_cast<const bf16x8*>(rp + 2 * DMODEL + d0);
    }
    *reinterpret_cast<bf16x8*>(&sKP[r * KST + d0]) = kv;
#pragma unroll
    for (int jj = 0; jj < 8; ++jj) {
      int dd = (jj + c) & 7;
      sVT[(d0 + dd) * PST + r] = (unsigned short)vv[dd];
    }
  }
  // ---- stage Q [64][KST] ----
#pragma unroll
  for (int it = 0; it < 2; ++it) {
    int c  = it * 256 + tid;         // 0..511
    int r  = c >> 3;                 // query row 0..63
    int d0 = (c & 7) * 8;
    bf16x8 qv = *reinterpret_cast<const bf16x8*>(hb + (size_t)(i0 + r) * 3072 + d0);
    *reinterpret_cast<bf16x8*>(&sQ[r * KST + d0]) = qv;
  }
  __syncthreads();

  const int q0 = wid * 16;

  // ---- phase 1: S^T = K @ Q^T  (12 MFMA) ----
  bf16x8 bq[2];
#pragma unroll
  for (int ks = 0; ks < 2; ++ks)
    bq[ks] = *reinterpret_cast<const bf16x8*>(
        &sQ[(q0 + qc) * KST + ks * 32 + lgrp * 8]);

  f32x4 st[6] = {};
#pragma unroll
  for (int kt = 0; kt < 6; ++kt) {
#pragma unroll
    for (int ks = 0; ks < 2; ++ks) {
      bf16x8 fa = *reinterpret_cast<const bf16x8*>(
          &sKP[(kt * 16 + qc) * KST + ks * 32 + lgrp * 8]);
      st[kt] = __builtin_amdgcn_mfma_f32_16x16x32_bf16(fa, bq[ks], st[kt], 0, 0, 0);
    }
  }
  __syncthreads();   // all waves done reading sKP before P overlays it

  // ---- mask + softmax ----
  const int q = q0 + qc;
  float pv[6][4];
  float mx = -3.0e38f;
#pragma unroll
  for (int kt = 0; kt < 6; ++kt)
#pragma unroll
    for (int rr = 0; rr < 4; ++rr) {
      int kk = kt * 16 + lgrp * 4 + rr;     // local key 0..95
      int j  = i0 - 16 + kk;
      bool ok = (j >= 0) && (j < S_LEN) && (kk >= q) && (kk <= q + 32);
      float s = ok ? st[kt][rr] * 0.125f : -3.0e38f;
      pv[kt][rr] = s;
      mx = fmaxf(mx, s);
    }
  mx = fmaxf(mx, __shfl_xor(mx, 16, 64));
  mx = fmaxf(mx, __shfl_xor(mx, 32, 64));

  float rsum = 0.f;
#pragma unroll
  for (int kt = 0; kt < 6; ++kt)
#pragma unroll
    for (int rr = 0; rr < 4; ++rr) {
      float p = __expf(pv[kt][rr] - mx);
      pv[kt][rr] = p;
      rsum += p;
    }
  rsum += __shfl_xor(rsum, 16, 64);
  rsum += __shfl_xor(rsum, 32, 64);
  const float inv = 1.0f / rsum;

  // ---- write unnormalized P bf16 into sP = sKP, layout [q][k] stride PST ----
  unsigned short* sP = sKP;
#pragma unroll
  for (int kt = 0; kt < 6; ++kt) {
    ushort4 w = make_ushort4(f2bf(pv[kt][0]), f2bf(pv[kt][1]),
                             f2bf(pv[kt][2]), f2bf(pv[kt][3]));
    *reinterpret_cast<ushort4*>(&sP[(q0 + qc) * PST + kt * 16 + lgrp * 4]) = w;
  }

  // ---- phase 2: ctx^T = V^T @ P^T  (12 MFMA) ----
  bf16x8 pb[3];
#pragma unroll
  for (int ks = 0; ks < 3; ++ks)
    pb[ks] = *reinterpret_cast<const bf16x8*>(
        &sP[(q0 + qc) * PST + ks * 32 + lgrp * 8]);

  f32x4 ct[4] = {};
#pragma unroll
  for (int dt = 0; dt < 4; ++dt)
#pragma unroll
    for (int ks = 0; ks < 3; ++ks) {
      bf16x8 fa = *reinterpret_cast<const bf16x8*>(
          &sVT[(dt * 16 + qc) * PST + ks * 32 + lgrp * 8]);
      ct[dt] = __builtin_amdgcn_mfma_f32_16x16x32_bf16(fa, pb[ks], ct[dt], 0, 0, 0);
    }

  // ---- epilogue ----
  unsigned short* op =
      ctx + ((size_t)b * S_LEN + i0 + q0 + qc) * DMODEL + h * HD;
#pragma unroll
  for (int dt = 0; dt < 4; ++dt) {
    ushort4 w = make_ushort4(
        f2bf(ct[dt][0] * inv), f2bf(ct[dt][1] * inv),
        f2bf(ct[dt][2] * inv), f2bf(ct[dt][3] * inv));
    *reinterpret_cast<ushort4*>(op + dt * 16 + lgrp * 4) = w;
  }
}

// ---------------------------------------------------------------------------
extern "C" void kernel_launch(void* const* d_in, const int* in_sizes, int n_in,
                              void* d_out, int out_size, void* d_ws, size_t ws_size,
                              hipStream_t stream) {
  const float* x     = (const float*)d_in[0];
  const float* w_in  = (const float*)d_in[1];
  const float* b_in  = (const float*)d_in[2];
  const float* w_out = (const float*)d_in[3];
  const float* b_out = (const float*)d_in[4];
  float* out = (float*)d_out;

  // workspace layout (bf16 = ushort), total ~92 MB
  unsigned short* xb   = (unsigned short*)d_ws;
  unsigned short* wib  = xb  + (size_t)8192 * 1024;
  unsigned short* wob  = wib + (size_t)3072 * 1024;
  unsigned short* qkv  = wob + (size_t)1024 * 1024;
  unsigned short* ctxb = qkv + (size_t)8192 * 3072;

  cvt_bf16_kernel<<<8192, 256, 0, stream>>>(x, xb, (8192 * 1024) / 4);
  cvt_bf16_kernel<<<3072, 256, 0, stream>>>(w_in, wib, (3072 * 1024) / 4);
  cvt_bf16_kernel<<<1024, 256, 0, stream>>>(w_out, wob, (1024 * 1024) / 4);

  // QKV = x @ w_in^T + b_in -> [8192, 3072] bf16; tile 256x384, grid 256 (1 round)
  gemm_inproj_kernel<<<256, 512, 0, stream>>>(xb, wib, b_in, qkv);

  // windowed attention -> ctx [8192, 1024] bf16
  attn_local_kernel<<<BATCHN * NH * (S_LEN / 64), 256, 0, stream>>>(qkv, ctxb);

  // out = ctx @ w_out^T + b_out -> [8192, 1024] f32; tile 128x256, grid 256
  gemm_outproj_kernel<<<256, 512, 0, stream>>>(ctxb, wob, b_out, out);
}